// Round 1
// baseline (12565.889 us; speedup 1.0000x reference)
//
#include <hip/hip_runtime.h>
#include <hip/hip_bf16.h>

// DGWA: deformable shifted-window attention, fully fused, one block per window.
// B=8, img 256x256, C=128, WS=8 (p2=64 tokens/window), w1=w2=32, heads=4, hd=32.
// Key identities used:
//  - cyclic shift by -4 == index (r+4)&255 on load; inverse roll == same map on store
//  - grid_sample(align_corners=True) normalization cancels: pixel coord = raw offset+grid
//  - oi / off_intra are per-window local -> whole net fuses into one kernel, no workspace

#define WS_    8
#define SHIFT_ 4
#define C_     128
#define IMG_   256
#define HEADS_ 4
#define LDSTR  132   // LDS row stride in floats: 128+4 pad (16B-aligned rows, no 32-bank alias)

__global__ __launch_bounds__(256, 2)
void dgwa_fused(const float* __restrict__ x,
                const float* __restrict__ rpp,
                const float* __restrict__ wi_w, const float* __restrict__ wi_b,
                const float* __restrict__ w1_w, const float* __restrict__ w1_b,
                const float* __restrict__ w2_w, const float* __restrict__ w2_b,
                const float* __restrict__ q_w,  const float* __restrict__ q_b,
                const float* __restrict__ kv_w, const float* __restrict__ kv_b,
                const float* __restrict__ o_w,  const float* __restrict__ o_b,
                float* __restrict__ out)
{
    __shared__ float s_b[64][LDSTR];       // xd -> v -> o-proj staging
    __shared__ float s_c[64][LDSTR];       // xd2 -> k -> attn-out
    __shared__ float s_rpp[HEADS_*15*15];  // 900 floats
    __shared__ float s_off[128];           // off_intra per token (x,y)
    __shared__ float s_red[128];           // oi_pre staging
    __shared__ float s_oi[2];              // per-window inter offset

    const int t   = threadIdx.x;
    const int win = blockIdx.x;
    const int bb  = win >> 10;
    const int wy  = (win >> 5) & 31;
    const int wx  = win & 31;

    // ---------------- P0: offset projections (wi: per-token, w1->w2: per-window) ----
    {
        const int tok = t >> 2, part = t & 3;
        const int i = tok >> 3, j = tok & 7;
        const int grow = (wy*8 + i + SHIFT_) & 255;
        const int gcol = (wx*8 + j + SHIFT_) & 255;
        const float* xr = x + (((size_t)bb*IMG_ + grow)*IMG_ + gcol)*C_ + part*32;
        float di0 = 0.f, di1 = 0.f, d10 = 0.f, d11 = 0.f;
        #pragma unroll
        for (int k4 = 0; k4 < 8; ++k4) {
            const float4 a4 = *(const float4*)(xr + k4*4);
            const int ch = part*32 + k4*4;
            di0 += a4.x*wi_w[(ch+0)*2+0] + a4.y*wi_w[(ch+1)*2+0] + a4.z*wi_w[(ch+2)*2+0] + a4.w*wi_w[(ch+3)*2+0];
            di1 += a4.x*wi_w[(ch+0)*2+1] + a4.y*wi_w[(ch+1)*2+1] + a4.z*wi_w[(ch+2)*2+1] + a4.w*wi_w[(ch+3)*2+1];
            d10 += a4.x*w1_w[(ch+0)*2+0] + a4.y*w1_w[(ch+1)*2+0] + a4.z*w1_w[(ch+2)*2+0] + a4.w*w1_w[(ch+3)*2+0];
            d11 += a4.x*w1_w[(ch+0)*2+1] + a4.y*w1_w[(ch+1)*2+1] + a4.z*w1_w[(ch+2)*2+1] + a4.w*w1_w[(ch+3)*2+1];
        }
        // reduce over the 4 channel-parts (adjacent lanes, bits 0..1)
        di0 += __shfl_xor(di0, 1); di0 += __shfl_xor(di0, 2);
        di1 += __shfl_xor(di1, 1); di1 += __shfl_xor(di1, 2);
        d10 += __shfl_xor(d10, 1); d10 += __shfl_xor(d10, 2);
        d11 += __shfl_xor(d11, 1); d11 += __shfl_xor(d11, 2);
        if (part == 0) {
            s_off[tok*2+0] = di0 + wi_b[0];
            s_off[tok*2+1] = di1 + wi_b[1];
            s_red[tok*2+0] = d10 + w1_b[0];   // includes w1_b, as in reference
            s_red[tok*2+1] = d11 + w1_b[1];
        }
    }
    for (int idx = t; idx < HEADS_*15*15; idx += 256) s_rpp[idx] = rpp[idx];
    __syncthreads();
    if (t < 64) {  // wave 0: oi = oi_pre(flattened tok,comp) @ w2_w + w2_b
        const float a0 = s_red[t*2+0], a1 = s_red[t*2+1];
        float p0 = a0*w2_w[(t*2+0)*2+0] + a1*w2_w[(t*2+1)*2+0];
        float p1 = a0*w2_w[(t*2+0)*2+1] + a1*w2_w[(t*2+1)*2+1];
        #pragma unroll
        for (int m = 1; m < 64; m <<= 1) { p0 += __shfl_xor(p0, m); p1 += __shfl_xor(p1, m); }
        if (t == 0) { s_oi[0] = p0 + w2_b[0]; s_oi[1] = p1 + w2_b[1]; }
    }
    __syncthreads();

    // ---------------- P1: inter-window bilinear sample -> s_b (xd) -------------------
    {
        const float gx = (float)wx + s_oi[0];
        const float gy = (float)wy + s_oi[1];
        const float fx0 = floorf(gx), fy0 = floorf(gy);
        const int   ix0 = (int)fx0,  iy0 = (int)fy0;
        const float fx = gx - fx0,   fy = gy - fy0;
        const float cw[4]  = { (1.f-fx)*(1.f-fy), fx*(1.f-fy), (1.f-fx)*fy, fx*fy };
        const int   cxs[4] = { ix0, ix0+1, ix0,   ix0+1 };
        const int   cys[4] = { iy0, iy0,   iy0+1, iy0+1 };
        const int v4 = t & 31;
        #pragma unroll
        for (int r = 0; r < 8; ++r) {
            const int tok = (t >> 5) + r*8;
            const int i = tok >> 3, j = tok & 7;
            float4 acc = make_float4(0.f, 0.f, 0.f, 0.f);
            #pragma unroll
            for (int cc = 0; cc < 4; ++cc) {
                const int cx = cxs[cc], cy = cys[cc];
                if (cx >= 0 && cx < 32 && cy >= 0 && cy < 32) {   // wave-uniform branch
                    const int rr = (cy*8 + i + SHIFT_) & 255;
                    const int cl = (cx*8 + j + SHIFT_) & 255;
                    const float4 vv = *(const float4*)(x + (((size_t)bb*IMG_ + rr)*IMG_ + cl)*C_ + v4*4);
                    const float w = cw[cc];
                    acc.x += w*vv.x; acc.y += w*vv.y; acc.z += w*vv.z; acc.w += w*vv.w;
                }
            }
            *(float4*)&s_b[tok][v4*4] = acc;
        }
    }
    __syncthreads();

    // ---------------- P2: intra-window bilinear sample -> s_c (xd2) ------------------
    {
        const int v4 = t & 31;
        #pragma unroll
        for (int r = 0; r < 8; ++r) {
            const int tok = (t >> 5) + r*8;
            const int i = tok >> 3, j = tok & 7;
            const float sx = (float)j + s_off[tok*2+0];
            const float sy = (float)i + s_off[tok*2+1];
            const float fx0 = floorf(sx), fy0 = floorf(sy);
            const int   jx0 = (int)fx0,  jy0 = (int)fy0;
            const float fx = sx - fx0,   fy = sy - fy0;
            float4 acc = make_float4(0.f, 0.f, 0.f, 0.f);
            #pragma unroll
            for (int cc = 0; cc < 4; ++cc) {
                const int cx = jx0 + (cc & 1), cy = jy0 + (cc >> 1);
                const float w = ((cc & 1) ? fx : 1.f-fx) * ((cc >> 1) ? fy : 1.f-fy);
                if (cx >= 0 && cx < 8 && cy >= 0 && cy < 8) {
                    const float4 vv = *(const float4*)&s_b[cy*8+cx][v4*4];
                    acc.x += w*vv.x; acc.y += w*vv.y; acc.z += w*vv.z; acc.w += w*vv.w;
                }
            }
            *(float4*)&s_c[tok][v4*4] = acc;
        }
    }
    __syncthreads();

    // ---------------- P3: k,v = xd2 @ kv_w + kv_b  (k->s_c, v->s_b) ------------------
    {
        const int tok = t >> 2, part = t & 3;
        float ka[32], va[32];
        #pragma unroll
        for (int jj = 0; jj < 32; ++jj) { ka[jj] = kv_b[part*32+jj]; va[jj] = kv_b[128+part*32+jj]; }
        for (int k4 = 0; k4 < 32; ++k4) {
            const float4 a4 = *(const float4*)&s_c[tok][k4*4];
            const float* wr = kv_w + (size_t)(k4*4)*256 + part*32;
            #pragma unroll
            for (int jj = 0; jj < 32; ++jj) {
                ka[jj] += a4.x*wr[jj]     + a4.y*wr[256+jj] + a4.z*wr[512+jj] + a4.w*wr[768+jj];
                va[jj] += a4.x*wr[128+jj] + a4.y*wr[384+jj] + a4.z*wr[640+jj] + a4.w*wr[896+jj];
            }
        }
        __syncthreads();   // all xd2 reads done before overwrite
        #pragma unroll
        for (int jj4 = 0; jj4 < 8; ++jj4) {
            *(float4*)&s_c[tok][part*32 + jj4*4] = make_float4(ka[jj4*4+0], ka[jj4*4+1], ka[jj4*4+2], ka[jj4*4+3]);
            *(float4*)&s_b[tok][part*32 + jj4*4] = make_float4(va[jj4*4+0], va[jj4*4+1], va[jj4*4+2], va[jj4*4+3]);
        }
    }
    __syncthreads();

    // ---------------- P4: q (from xw), sim, bias+mask, softmax, PV -------------------
    {
        const int h = t >> 6, qrow = t & 63;   // one wave per head
        const int ip = qrow >> 3, jp = qrow & 7;
        float qreg[32];
        #pragma unroll
        for (int d = 0; d < 32; ++d) qreg[d] = q_b[h*32+d];
        {
            const int grow = (wy*8 + ip + SHIFT_) & 255;
            const int gcol = (wx*8 + jp + SHIFT_) & 255;
            const float* xr = x + (((size_t)bb*IMG_ + grow)*IMG_ + gcol)*C_;
            for (int k4 = 0; k4 < 32; ++k4) {
                const float4 a4 = *(const float4*)(xr + k4*4);
                const float* wr = q_w + (size_t)(k4*4)*C_ + h*32;
                #pragma unroll
                for (int d = 0; d < 32; ++d)
                    qreg[d] += a4.x*wr[d] + a4.y*wr[C_+d] + a4.z*wr[2*C_+d] + a4.w*wr[3*C_+d];
            }
        }
        float sim[64];
        const bool mrow = (wy == 31), mcol = (wx == 31);
        #pragma unroll 8
        for (int kq = 0; kq < 64; ++kq) {
            const int ik = kq >> 3, jk = kq & 7;
            float d0 = 0.f;
            #pragma unroll
            for (int d4 = 0; d4 < 8; ++d4) {
                const float4 kk4 = *(const float4*)&s_c[kq][h*32 + d4*4];
                d0 += qreg[d4*4+0]*kk4.x + qreg[d4*4+1]*kk4.y + qreg[d4*4+2]*kk4.z + qreg[d4*4+3]*kk4.w;
            }
            const float sv = d0 * 0.1767766952966369f
                           + s_rpp[h*225 + (ip-ik+7)*15 + (jp-jk+7)];
            const bool masked = (mrow && ((ip < 4) != (ik < 4))) || (mcol && ((jp < 4) != (jk < 4)));
            sim[kq] = masked ? -1e30f : sv;
        }
        float mx = -1e30f;
        #pragma unroll
        for (int kq = 0; kq < 64; ++kq) mx = fmaxf(mx, sim[kq]);
        float ssum = 0.f;
        #pragma unroll
        for (int kq = 0; kq < 64; ++kq) { const float e = __expf(sim[kq] - mx); sim[kq] = e; ssum += e; }
        const float rs = 1.f / ssum;
        float attn[32];
        #pragma unroll
        for (int d = 0; d < 32; ++d) attn[d] = 0.f;
        #pragma unroll 8
        for (int kq = 0; kq < 64; ++kq) {
            const float p = sim[kq] * rs;
            #pragma unroll
            for (int d4 = 0; d4 < 8; ++d4) {
                const float4 vv4 = *(const float4*)&s_b[kq][h*32 + d4*4];
                attn[d4*4+0] += p*vv4.x; attn[d4*4+1] += p*vv4.y;
                attn[d4*4+2] += p*vv4.z; attn[d4*4+3] += p*vv4.w;
            }
        }
        __syncthreads();   // k/v fully consumed by all threads before overwrite
        #pragma unroll
        for (int d4 = 0; d4 < 8; ++d4)
            *(float4*)&s_c[qrow][h*32 + d4*4]
                = make_float4(attn[d4*4+0], attn[d4*4+1], attn[d4*4+2], attn[d4*4+3]);
    }
    __syncthreads();

    // ---------------- P5: out = attn @ o_w + o_b -> stage s_b ------------------------
    {
        const int tok = t >> 2, part = t & 3;
        float acc[32];
        #pragma unroll
        for (int jj = 0; jj < 32; ++jj) acc[jj] = o_b[part*32+jj];
        for (int k4 = 0; k4 < 32; ++k4) {
            const float4 a4 = *(const float4*)&s_c[tok][k4*4];
            const float* wr = o_w + (size_t)(k4*4)*C_ + part*32;
            #pragma unroll
            for (int jj = 0; jj < 32; ++jj)
                acc[jj] += a4.x*wr[jj] + a4.y*wr[C_+jj] + a4.z*wr[2*C_+jj] + a4.w*wr[3*C_+jj];
        }
        #pragma unroll
        for (int jj4 = 0; jj4 < 8; ++jj4)
            *(float4*)&s_b[tok][part*32 + jj4*4]
                = make_float4(acc[jj4*4+0], acc[jj4*4+1], acc[jj4*4+2], acc[jj4*4+3]);
    }
    __syncthreads();

    // ---------------- coalesced store with inverse roll ------------------------------
    {
        const int v4 = t & 31;
        #pragma unroll
        for (int r = 0; r < 8; ++r) {
            const int tok = (t >> 5) + r*8;
            const int i = tok >> 3, j = tok & 7;
            const int orow = (wy*8 + i + SHIFT_) & 255;
            const int ocol = (wx*8 + j + SHIFT_) & 255;
            const float4 vv = *(const float4*)&s_b[tok][v4*4];
            *(float4*)(out + (((size_t)bb*IMG_ + orow)*IMG_ + ocol)*C_ + v4*4) = vv;
        }
    }
}

extern "C" void kernel_launch(void* const* d_in, const int* in_sizes, int n_in,
                              void* d_out, int out_size, void* d_ws, size_t ws_size,
                              hipStream_t stream) {
    (void)in_sizes; (void)n_in; (void)out_size; (void)d_ws; (void)ws_size;
    const float* x    = (const float*)d_in[0];
    const float* rpp  = (const float*)d_in[1];
    const float* wi_w = (const float*)d_in[2];
    const float* wi_b = (const float*)d_in[3];
    const float* w1_w = (const float*)d_in[4];
    const float* w1_b = (const float*)d_in[5];
    const float* w2_w = (const float*)d_in[6];
    const float* w2_b = (const float*)d_in[7];
    const float* q_w  = (const float*)d_in[8];
    const float* q_b  = (const float*)d_in[9];
    const float* kv_w = (const float*)d_in[10];
    const float* kv_b = (const float*)d_in[11];
    const float* o_w  = (const float*)d_in[12];
    const float* o_b  = (const float*)d_in[13];
    float* out = (float*)d_out;

    dgwa_fused<<<dim3(8192), dim3(256), 0, stream>>>(
        x, rpp, wi_w, wi_b, w1_w, w1_b, w2_w, w2_b,
        q_w, q_b, kv_w, kv_b, o_w, o_b, out);
}

// Round 2
// 913.844 us; speedup vs baseline: 13.7506x; 13.7506x over previous
//
#include <hip/hip_runtime.h>
#include <hip/hip_bf16.h>

// DGWA fused, MFMA version.
// One block per window (8192 blocks x 512 threads, 1 block/CU, ~148KB LDS).
// All matmuls on v_mfma_f32_16x16x32_bf16 with K-contiguous LDS layouts:
//   A-frag: A[m=lane&15][k=quad*8+j]   (row-major [M][K])
//   B-frag: B[k=quad*8+j][n=lane&15]   (store B^T row-major [N][K])
//   C/D:    row=quad*4+reg, col=lane&15
// Chain trick: sim^T = K·Q^T, out^T = V^T·P, final^T = o_w^T·attn -> every
// operand reads natural K-contiguous rows (ds_read_b128), every transpose is
// a 2-way-conflict bf16 scatter from C-frags.
// Prep kernel packs transposed bf16 weights into d_ws once per call.

#define WS_    8
#define SHIFT_ 4
#define C_     128
#define IMG_   256

typedef __attribute__((ext_vector_type(8))) short short8;
typedef __attribute__((ext_vector_type(4))) short short4v;
typedef __attribute__((ext_vector_type(4))) float f32x4;

#define MFMA(a,b,c) __builtin_amdgcn_mfma_f32_16x16x32_bf16((a),(b),(c),0,0,0)

__device__ __forceinline__ short f2bf(float f){
    unsigned u = __float_as_uint(f);
    u = u + 0x7fffu + ((u >> 16) & 1u);   // round-to-nearest-even
    return (short)(u >> 16);
}
__device__ __forceinline__ float bf2f(short s){
    return __uint_as_float(((unsigned)(unsigned short)s) << 16);
}

// ws (bf16): [0,16384) q_wT[cout][cin]; [16384,49152) kv_wT[cout][cin]; [49152,65536) o_wT[cout][cin]
__global__ void dgwa_prep(const float* __restrict__ q_w, const float* __restrict__ kv_w,
                          const float* __restrict__ o_w, short* __restrict__ ws){
    int idx = blockIdx.x*256 + threadIdx.x;
    if (idx < 16384){ int co = idx>>7, ci = idx&127; ws[idx] = f2bf(q_w[ci*128 + co]); }
    else if (idx < 49152){ int i = idx-16384; int co = i>>7, ci = i&127; ws[idx] = f2bf(kv_w[ci*256 + co]); }
    else { int i = idx-49152; int co = i>>7, ci = i&127; ws[idx] = f2bf(o_w[ci*128 + co]); }
}

__global__ __launch_bounds__(512, 2)
void dgwa_fused(const float* __restrict__ x, const float* __restrict__ rpp,
                const float* __restrict__ wi_w, const float* __restrict__ wi_b,
                const float* __restrict__ w1_w, const float* __restrict__ w1_b,
                const float* __restrict__ w2_w, const float* __restrict__ w2_b,
                const float* __restrict__ q_b,  const float* __restrict__ kv_b,
                const float* __restrict__ o_b,
                const short* __restrict__ wsw,
                float* __restrict__ out)
{
    // Region map (byte offsets), phase-aliased:
    //   [0)        s_w   [256][136] bf16 kv_wT (P3) / q_wT, o_wT in rows 0..127 (P4/P7)
    //              s_xd  [64][136]  alias (live P1->P2 only)
    //   [34816)    s_p   [4][64][72] bf16 (P5->P6)
    //   [72704)    s_xw  [64][136]  xw (P0->P4) -> q (P4->P5) -> attn (P6->P7)
    //   [90112)    s_xd2 [64][136]  (P2->P3); s_outT [128][65] f32 (P7->P8, spans s_k too)
    //   [107520)   s_k   [64][136]  (P3->P5)
    //   [124928)   s_vT  [128][72]  (P3->P6)
    //   [143360)   s_rpp[900] f32; [146960) s_off[128]; [147472) s_red[128]; [147984) s_oi[2]
    __shared__ __align__(16) char smem[147992];
    short* s_w    = (short*)(smem);
    short* s_xd   = (short*)(smem);
    short* s_p    = (short*)(smem + 34816);
    short* s_xw   = (short*)(smem + 72704);
    short* s_xd2  = (short*)(smem + 90112);
    float* s_outT = (float*)(smem + 90112);
    short* s_k    = (short*)(smem + 107520);
    short* s_vT   = (short*)(smem + 124928);
    float* s_rpp  = (float*)(smem + 143360);
    float* s_off  = (float*)(smem + 146960);
    float* s_red  = (float*)(smem + 147472);
    float* s_oi   = (float*)(smem + 147984);

    const int t   = threadIdx.x;
    const int wv  = t >> 6, l = t & 63, l15 = l & 15, quad = l >> 4;
    const int win = blockIdx.x;
    const int bb  = win >> 10, wy = (win >> 5) & 31, wx = win & 31;
    const f32x4 zf = {0.f, 0.f, 0.f, 0.f};

    // ---------------- P0: offset projections + stage xw (bf16) ----------------------
    {
        const int tok = t >> 3, part = t & 7;          // 16 chans per thread
        const int i = tok >> 3, j = tok & 7;
        const int grow = (wy*8 + i + SHIFT_) & 255;
        const int gcol = (wx*8 + j + SHIFT_) & 255;
        const float* xr = x + (((size_t)bb*IMG_ + grow)*IMG_ + gcol)*C_ + part*16;
        float di0=0.f, di1=0.f, d10=0.f, d11=0.f;
        #pragma unroll
        for (int c4 = 0; c4 < 4; ++c4){
            const float4 a4 = *(const float4*)(xr + c4*4);
            const int ch = part*16 + c4*4;
            di0 += a4.x*wi_w[ch*2+0]+a4.y*wi_w[ch*2+2]+a4.z*wi_w[ch*2+4]+a4.w*wi_w[ch*2+6];
            di1 += a4.x*wi_w[ch*2+1]+a4.y*wi_w[ch*2+3]+a4.z*wi_w[ch*2+5]+a4.w*wi_w[ch*2+7];
            d10 += a4.x*w1_w[ch*2+0]+a4.y*w1_w[ch*2+2]+a4.z*w1_w[ch*2+4]+a4.w*w1_w[ch*2+6];
            d11 += a4.x*w1_w[ch*2+1]+a4.y*w1_w[ch*2+3]+a4.z*w1_w[ch*2+5]+a4.w*w1_w[ch*2+7];
            short4v sv = { f2bf(a4.x), f2bf(a4.y), f2bf(a4.z), f2bf(a4.w) };
            *(short4v*)&s_xw[tok*136 + part*16 + c4*4] = sv;
        }
        di0 += __shfl_xor(di0,1); di0 += __shfl_xor(di0,2); di0 += __shfl_xor(di0,4);
        di1 += __shfl_xor(di1,1); di1 += __shfl_xor(di1,2); di1 += __shfl_xor(di1,4);
        d10 += __shfl_xor(d10,1); d10 += __shfl_xor(d10,2); d10 += __shfl_xor(d10,4);
        d11 += __shfl_xor(d11,1); d11 += __shfl_xor(d11,2); d11 += __shfl_xor(d11,4);
        if (part == 0){
            s_off[tok*2+0] = di0 + wi_b[0];
            s_off[tok*2+1] = di1 + wi_b[1];
            s_red[tok*2+0] = d10 + w1_b[0];
            s_red[tok*2+1] = d11 + w1_b[1];
        }
    }
    for (int idx = t; idx < 900; idx += 512) s_rpp[idx] = rpp[idx];
    __syncthreads();
    if (t < 64){
        const float a0 = s_red[t*2+0], a1 = s_red[t*2+1];
        float p0 = a0*w2_w[(t*2+0)*2+0] + a1*w2_w[(t*2+1)*2+0];
        float p1 = a0*w2_w[(t*2+0)*2+1] + a1*w2_w[(t*2+1)*2+1];
        #pragma unroll
        for (int m = 1; m < 64; m <<= 1){ p0 += __shfl_xor(p0,m); p1 += __shfl_xor(p1,m); }
        if (t == 0){ s_oi[0] = p0 + w2_b[0]; s_oi[1] = p1 + w2_b[1]; }
    }
    __syncthreads();

    // ---------------- P1: inter-window bilinear sample -> s_xd (bf16) ---------------
    {
        const int tok = t >> 3, part = t & 7;
        const int i = tok >> 3, j = tok & 7;
        const float gx = (float)wx + s_oi[0];
        const float gy = (float)wy + s_oi[1];
        const float fx0 = floorf(gx), fy0 = floorf(gy);
        const int ix0 = (int)fx0, iy0 = (int)fy0;
        const float fx = gx - fx0, fy = gy - fy0;
        const float cw[4] = {(1.f-fx)*(1.f-fy), fx*(1.f-fy), (1.f-fx)*fy, fx*fy};
        float4 acc4[4];
        #pragma unroll
        for (int c4 = 0; c4 < 4; ++c4) acc4[c4] = make_float4(0.f,0.f,0.f,0.f);
        #pragma unroll
        for (int cc = 0; cc < 4; ++cc){
            const int cx = ix0 + (cc & 1), cy = iy0 + (cc >> 1);
            if (cx >= 0 && cx < 32 && cy >= 0 && cy < 32){    // wave-uniform
                const int rr = (cy*8 + i + SHIFT_) & 255;
                const int cl = (cx*8 + j + SHIFT_) & 255;
                const float* p = x + (((size_t)bb*IMG_ + rr)*IMG_ + cl)*C_ + part*16;
                const float w = cw[cc];
                #pragma unroll
                for (int c4 = 0; c4 < 4; ++c4){
                    const float4 v = *(const float4*)(p + c4*4);
                    acc4[c4].x += w*v.x; acc4[c4].y += w*v.y;
                    acc4[c4].z += w*v.z; acc4[c4].w += w*v.w;
                }
            }
        }
        #pragma unroll
        for (int c4 = 0; c4 < 4; ++c4){
            short4v sv = { f2bf(acc4[c4].x), f2bf(acc4[c4].y), f2bf(acc4[c4].z), f2bf(acc4[c4].w) };
            *(short4v*)&s_xd[tok*136 + part*16 + c4*4] = sv;
        }
    }
    __syncthreads();

    // ---------------- P2: intra-window bilinear sample -> s_xd2 (bf16) --------------
    {
        const int tok = t >> 3, part = t & 7;
        const int i = tok >> 3, j = tok & 7;
        const float sx = (float)j + s_off[tok*2+0];
        const float sy = (float)i + s_off[tok*2+1];
        const float fx0 = floorf(sx), fy0 = floorf(sy);
        const int jx0 = (int)fx0, jy0 = (int)fy0;
        const float fx = sx - fx0, fy = sy - fy0;
        float4 acc4[4];
        #pragma unroll
        for (int c4 = 0; c4 < 4; ++c4) acc4[c4] = make_float4(0.f,0.f,0.f,0.f);
        #pragma unroll
        for (int cc = 0; cc < 4; ++cc){
            const int cx = jx0 + (cc & 1), cy = jy0 + (cc >> 1);
            const float w = ((cc & 1) ? fx : 1.f-fx) * ((cc >> 1) ? fy : 1.f-fy);
            if (cx >= 0 && cx < 8 && cy >= 0 && cy < 8){
                const short* p = &s_xd[(cy*8 + cx)*136 + part*16];
                #pragma unroll
                for (int c4 = 0; c4 < 4; ++c4){
                    const short4v sv = *(const short4v*)(p + c4*4);
                    acc4[c4].x += w*bf2f(sv.x); acc4[c4].y += w*bf2f(sv.y);
                    acc4[c4].z += w*bf2f(sv.z); acc4[c4].w += w*bf2f(sv.w);
                }
            }
        }
        #pragma unroll
        for (int c4 = 0; c4 < 4; ++c4){
            short4v sv = { f2bf(acc4[c4].x), f2bf(acc4[c4].y), f2bf(acc4[c4].z), f2bf(acc4[c4].w) };
            *(short4v*)&s_xd2[tok*136 + part*16 + c4*4] = sv;
        }
    }
    __syncthreads();

    // ---------------- P3: stage kv_wT; kv = xd2 @ kv_w  (k -> s_k, v -> s_vT) -------
    {
        const short* src = wsw + 16384;
        #pragma unroll
        for (int r8 = 0; r8 < 8; ++r8){
            const int e = (r8*512 + t)*8;
            *(short8*)&s_w[(e>>7)*136 + (e&127)] = *(const short8*)&src[e];
        }
    }
    __syncthreads();
    {
        f32x4 acc[2][4];
        #pragma unroll
        for (int nn = 0; nn < 2; ++nn)
            #pragma unroll
            for (int mt = 0; mt < 4; ++mt) acc[nn][mt] = zf;
        #pragma unroll
        for (int ks = 0; ks < 4; ++ks){
            const int co = ks*32 + quad*8;
            const short8 b0 = *(const short8*)&s_w[(32*wv +      l15)*136 + co];
            const short8 b1 = *(const short8*)&s_w[(32*wv + 16 + l15)*136 + co];
            #pragma unroll
            for (int mt = 0; mt < 4; ++mt){
                const short8 a = *(const short8*)&s_xd2[(16*mt + l15)*136 + co];
                acc[0][mt] = MFMA(a, b0, acc[0][mt]);
                acc[1][mt] = MFMA(a, b1, acc[1][mt]);
            }
        }
        #pragma unroll
        for (int nn = 0; nn < 2; ++nn){
            const int col = 32*wv + 16*nn + l15;
            const float bias = kv_b[col];
            #pragma unroll
            for (int mt = 0; mt < 4; ++mt){
                #pragma unroll
                for (int r = 0; r < 4; ++r){
                    const int tokr = 16*mt + 4*quad + r;
                    const short v = f2bf(acc[nn][mt][r] + bias);
                    if (col < 128) s_k[tokr*136 + col] = v;          // waves 0..3
                    else           s_vT[(col-128)*72 + tokr] = v;    // waves 4..7 (transposed)
                }
            }
        }
    }
    __syncthreads();

    // ---------------- P4: stage q_wT; q = xw @ q_w -> s_q (in s_xw region) ----------
    {
        #pragma unroll
        for (int r4 = 0; r4 < 4; ++r4){
            const int e = (r4*512 + t)*8;
            *(short8*)&s_w[(e>>7)*136 + (e&127)] = *(const short8*)&wsw[e];
        }
    }
    __syncthreads();
    {
        f32x4 qacc[4];
        #pragma unroll
        for (int mt = 0; mt < 4; ++mt) qacc[mt] = zf;
        #pragma unroll
        for (int ks = 0; ks < 4; ++ks){
            const int co = ks*32 + quad*8;
            const short8 b = *(const short8*)&s_w[(16*wv + l15)*136 + co];
            #pragma unroll
            for (int mt = 0; mt < 4; ++mt){
                const short8 a = *(const short8*)&s_xw[(16*mt + l15)*136 + co];
                qacc[mt] = MFMA(a, b, qacc[mt]);
            }
        }
        __syncthreads();     // all s_xw reads complete before q overwrites it
        const int col = 16*wv + l15;
        const float bias = q_b[col];
        #pragma unroll
        for (int mt = 0; mt < 4; ++mt)
            #pragma unroll
            for (int r = 0; r < 4; ++r)
                s_xw[(16*mt + 4*quad + r)*136 + col] = f2bf(qacc[mt][r] + bias);
    }
    __syncthreads();

    // ---------------- P5: waves 0-3: sim^T = K·Q^T, softmax, P -> s_p ---------------
    //                  waves 4-7: stage o_wT into s_w rows 0..127
    if (wv < 4){
        const int h = wv;
        short8 a[4], bq[4];
        #pragma unroll
        for (int mt = 0; mt < 4; ++mt)
            a[mt]  = *(const short8*)&s_k [(16*mt + l15)*136 + 32*h + quad*8];
        #pragma unroll
        for (int nt = 0; nt < 4; ++nt)
            bq[nt] = *(const short8*)&s_xw[(16*nt + l15)*136 + 32*h + quad*8];  // q
        f32x4 sc[4][4];
        #pragma unroll
        for (int mt = 0; mt < 4; ++mt)
            #pragma unroll
            for (int nt = 0; nt < 4; ++nt)
                sc[mt][nt] = MFMA(a[mt], bq[nt], zf);
        const bool mrow = (wy == 31), mcol = (wx == 31);
        float rs[4];
        #pragma unroll
        for (int nt = 0; nt < 4; ++nt){
            const int qtok = 16*nt + l15;
            const int iq = qtok >> 3, jq = qtok & 7;
            float ssum = 0.f;
            #pragma unroll
            for (int mt = 0; mt < 4; ++mt){
                #pragma unroll
                for (int r = 0; r < 4; ++r){
                    const int ktok = 16*mt + 4*quad + r;
                    const int ik = ktok >> 3, jk = ktok & 7;
                    const float sv = sc[mt][nt][r]*0.1767766952966369f
                                   + s_rpp[h*225 + (iq-ik+7)*15 + (jq-jk+7)];
                    const bool masked = (mrow && ((iq<4)!=(ik<4))) || (mcol && ((jq<4)!=(jk<4)));
                    const float e = masked ? 0.f : __expf(sv);   // |logit| small: no max-sub needed
                    sc[mt][nt][r] = e;
                    ssum += e;
                }
            }
            ssum += __shfl_xor(ssum, 16);
            ssum += __shfl_xor(ssum, 32);
            rs[nt] = 1.f / ssum;
        }
        #pragma unroll
        for (int nt = 0; nt < 4; ++nt){
            const int qtok = 16*nt + l15;
            #pragma unroll
            for (int mt = 0; mt < 4; ++mt)
                #pragma unroll
                for (int r = 0; r < 4; ++r){
                    const int ktok = 16*mt + 4*quad + r;
                    s_p[h*4608 + qtok*72 + ktok] = f2bf(sc[mt][nt][r] * rs[nt]);
                }
        }
    } else {
        const int tt = t - 256;
        const short* src = wsw + 49152;
        #pragma unroll
        for (int r8 = 0; r8 < 8; ++r8){
            const int e = (r8*256 + tt)*8;
            *(short8*)&s_w[(e>>7)*136 + (e&127)] = *(const short8*)&src[e];
        }
    }
    __syncthreads();

    // ---------------- P6: out^T = V^T · P  -> s_attn (in s_xw region) ---------------
    {
        const int h = wv >> 1, mh = wv & 1;
        short8 av[2];
        #pragma unroll
        for (int ks = 0; ks < 2; ++ks)
            av[ks] = *(const short8*)&s_vT[(32*h + 16*mh + l15)*72 + ks*32 + quad*8];
        f32x4 po[4];
        #pragma unroll
        for (int nt = 0; nt < 4; ++nt) po[nt] = zf;
        #pragma unroll
        for (int nt = 0; nt < 4; ++nt)
            #pragma unroll
            for (int ks = 0; ks < 2; ++ks){
                const short8 bp = *(const short8*)&s_p[h*4608 + (16*nt + l15)*72 + ks*32 + quad*8];
                po[nt] = MFMA(av[ks], bp, po[nt]);
            }
        #pragma unroll
        for (int nt = 0; nt < 4; ++nt){
            const int qtok = 16*nt + l15;
            #pragma unroll
            for (int r = 0; r < 4; ++r){
                const int drow = 32*h + 16*mh + 4*quad + r;
                s_xw[qtok*136 + drow] = f2bf(po[nt][r]);     // attn[tok][cin]
            }
        }
    }
    __syncthreads();

    // ---------------- P7: final^T = o_w^T · attn -> s_outT (f32, stride 65) ---------
    {
        f32x4 oc[4];
        #pragma unroll
        for (int nt = 0; nt < 4; ++nt) oc[nt] = zf;
        #pragma unroll
        for (int ks = 0; ks < 4; ++ks){
            const int co = ks*32 + quad*8;
            const short8 aw = *(const short8*)&s_w[(16*wv + l15)*136 + co];
            #pragma unroll
            for (int nt = 0; nt < 4; ++nt){
                const short8 bt = *(const short8*)&s_xw[(16*nt + l15)*136 + co];
                oc[nt] = MFMA(aw, bt, oc[nt]);
            }
        }
        const float4 ob = *(const float4*)&o_b[16*wv + 4*quad];
        const float obr[4] = {ob.x, ob.y, ob.z, ob.w};
        #pragma unroll
        for (int nt = 0; nt < 4; ++nt){
            const int tok = 16*nt + l15;
            #pragma unroll
            for (int r = 0; r < 4; ++r){
                const int cout = 16*wv + 4*quad + r;
                s_outT[cout*65 + tok] = oc[nt][r] + obr[r];
            }
        }
    }
    __syncthreads();

    // ---------------- P8: coalesced store with inverse roll -------------------------
    {
        const int chan = t & 127;
        #pragma unroll
        for (int it = 0; it < 16; ++it){
            const int tok = (t >> 7) + it*4;
            const int i = tok >> 3, j = tok & 7;
            const int orow = (wy*8 + i + SHIFT_) & 255;
            const int ocol = (wx*8 + j + SHIFT_) & 255;
            out[(((size_t)bb*IMG_ + orow)*IMG_ + ocol)*C_ + chan] = s_outT[chan*65 + tok];
        }
    }
}

extern "C" void kernel_launch(void* const* d_in, const int* in_sizes, int n_in,
                              void* d_out, int out_size, void* d_ws, size_t ws_size,
                              hipStream_t stream) {
    (void)in_sizes; (void)n_in; (void)out_size; (void)ws_size;
    const float* x    = (const float*)d_in[0];
    const float* rpp  = (const float*)d_in[1];
    const float* wi_w = (const float*)d_in[2];
    const float* wi_b = (const float*)d_in[3];
    const float* w1_w = (const float*)d_in[4];
    const float* w1_b = (const float*)d_in[5];
    const float* w2_w = (const float*)d_in[6];
    const float* w2_b = (const float*)d_in[7];
    const float* q_w  = (const float*)d_in[8];
    const float* q_b  = (const float*)d_in[9];
    const float* kv_w = (const float*)d_in[10];
    const float* kv_b = (const float*)d_in[11];
    const float* o_w  = (const float*)d_in[12];
    const float* o_b  = (const float*)d_in[13];
    float* out = (float*)d_out;
    short* ws  = (short*)d_ws;

    dgwa_prep<<<dim3(256), dim3(256), 0, stream>>>(q_w, kv_w, o_w, ws);
    dgwa_fused<<<dim3(8192), dim3(512), 0, stream>>>(
        x, rpp, wi_w, wi_b, w1_w, w1_b, w2_w, w2_b,
        q_b, kv_b, o_b, ws, out);
}